// Round 6
// baseline (656.349 us; speedup 1.0000x reference)
//
#include <hip/hip_runtime.h>
#include <hip/hip_fp16.h>
#include <math.h>

#define N_NODES 100000
#define N_EDGES 6400000
#define D_IN 512
#define D_HID 16

// ---- bucketed counting-sort parameters ----
#define BSHIFT 7
#define BNODES 128                                   // nodes per bucket
#define NB ((N_NODES + BNODES - 1) / BNODES)         // 782 buckets
#define NBP 800                                      // bhist row pitch
#define P2T 25600                                    // edges per tile (p1/p2)
#define NT2 (N_EDGES / P2T)                          // 250 (exact)
#define CAP 9728                                     // max edges/bucket (mean 8184 + ~17 sigma)

// ---------------- pass 1: per-tile bucket histogram (saved) ----------------
__global__ __launch_bounds__(1024) void p1_hist(const int* __restrict__ dst,
                                                int* __restrict__ bhist,
                                                int* __restrict__ bcnt) {
    __shared__ int h[NB];
    int tid = threadIdx.x;
    if (tid < NB) h[tid] = 0;
    __syncthreads();
    int base = blockIdx.x * P2T;
#pragma unroll
    for (int k = 0; k < P2T / 1024; k++) {
        int e = base + k * 1024 + tid;
        atomicAdd(&h[dst[e] >> BSHIFT], 1);
    }
    __syncthreads();
    if (tid < NB) {
        int c = h[tid];
        bhist[blockIdx.x * NBP + tid] = c;
        if (c) atomicAdd(&bcnt[tid], c);
    }
}

// ---------------- pass 2a: scan bucket counts (1 block) ----------------
__global__ void p2_scan(const int* __restrict__ bcnt, int* __restrict__ bstart,
                        int* __restrict__ bcur) {
    __shared__ int sd[1024];
    int tid = threadIdx.x;  // 1024 threads
    int v = (tid < NB) ? bcnt[tid] : 0;
    sd[tid] = v;
    __syncthreads();
    for (int off = 1; off < 1024; off <<= 1) {
        int u = (tid >= off) ? sd[tid - off] : 0;
        __syncthreads();
        sd[tid] += u;
        __syncthreads();
    }
    if (tid < NB) {
        int ex = sd[tid] - v;
        bstart[tid] = ex;
        bcur[tid] = ex;
    }
}

// ---------------- pass 2b: LDS-sorted multisplit scatter ----------------
__global__ __launch_bounds__(1024) void p2_scatter(const int* __restrict__ src,
                                                   const int* __restrict__ dst,
                                                   const int* __restrict__ bhist,
                                                   int* __restrict__ bcur,
                                                   unsigned int* __restrict__ staged) {
    __shared__ unsigned int sbuf[P2T];   // 100 KB
    __shared__ int loc[NB + 1];
    __shared__ int lcur[NB];
    __shared__ int gbase[NB];
    __shared__ int sd[1024];
    int tid = threadIdx.x;
    int blk = blockIdx.x;
    int c = 0;
    if (tid < NB) {
        c = bhist[blk * NBP + tid];
        gbase[tid] = c ? atomicAdd(&bcur[tid], c) : 0;
    }
    sd[tid] = (tid < NB) ? c : 0;
    __syncthreads();
    for (int off = 1; off < 1024; off <<= 1) {
        int u = (tid >= off) ? sd[tid - off] : 0;
        __syncthreads();
        sd[tid] += u;
        __syncthreads();
    }
    if (tid < NB) {
        int ex = sd[tid] - c;
        loc[tid] = ex;
        lcur[tid] = ex;
    }
    if (tid == 0) loc[NB] = P2T;  // sentinel (tile hist sums to P2T exactly)
    __syncthreads();
    int base = blk * P2T;
#pragma unroll
    for (int k = 0; k < P2T / 1024; k++) {
        int e = base + k * 1024 + tid;
        int d = dst[e];
        int b = d >> BSHIFT;
        int pos = atomicAdd(&lcur[b], 1);
        sbuf[pos] = ((unsigned int)src[e] << BSHIFT) | (unsigned int)(d & (BNODES - 1));
    }
    __syncthreads();
#pragma unroll
    for (int k = 0; k < P2T / 1024; k++) {
        int j = k * 1024 + tid;
        int lo = 0, hi = NB;
        while (hi - lo > 1) {
            int mid = (lo + hi) >> 1;
            if (loc[mid] <= j) lo = mid; else hi = mid;
        }
        staged[gbase[lo] + (j - loc[lo])] = sbuf[j];
    }
}

// ---------------- pass 3: per-bucket CSR build (+deg, row_start, dinv) ------
__global__ __launch_bounds__(512) void p3_build(unsigned int* __restrict__ ebuf,
                                                const int* __restrict__ bstart,
                                                const int* __restrict__ bcnt,
                                                int* __restrict__ row_start,
                                                int* __restrict__ deg,
                                                float* __restrict__ dinv) {
    __shared__ unsigned int buf[CAP];
    __shared__ int cnt[BNODES];
    __shared__ int cur[BNODES];
    int b = blockIdx.x;
    int tid = threadIdx.x;
    int ebase = bstart[b];
    int ecnt = bcnt[b];
    if (ecnt > CAP) ecnt = CAP;  // statistically impossible; guards LDS
    if (tid < BNODES) cnt[tid] = 0;
    __syncthreads();
    for (int i = tid; i < ecnt; i += 512) {
        unsigned int v = ebuf[ebase + i];
        buf[i] = v;
        atomicAdd(&cnt[v & (BNODES - 1)], 1);
    }
    __syncthreads();
    int c = 0;
    if (tid < BNODES) {
        c = cnt[tid];
        cur[tid] = c;
    }
    __syncthreads();
    for (int off = 1; off < BNODES; off <<= 1) {
        int u = 0;
        if (tid < BNODES && tid >= off) u = cur[tid - off];
        __syncthreads();
        if (tid < BNODES) cur[tid] += u;
        __syncthreads();
    }
    int excl = 0;
    if (tid < BNODES) excl = cur[tid] - c;
    int node = b * BNODES + tid;
    if (tid < BNODES && node < N_NODES) {
        row_start[node] = ebase + excl;
        deg[node] = c;
        dinv[node] = rsqrtf((float)c + 1.0f);  // +1 self-loop
    }
    __syncthreads();
    if (tid < BNODES) cur[tid] = excl;  // local cursor
    __syncthreads();
    for (int i = tid; i < ecnt; i += 512) {
        unsigned int v = buf[i];
        int pos = atomicAdd(&cur[v & (BNODES - 1)], 1);
        ebuf[ebase + pos] = v >> BSHIFT;  // final CSR: src id
    }
}

// ---------------- GEMM1: hs1 = fp16((x @ W1) * dinv[row]) ----------------
// Split-K: 256 threads = 64 rows x 4 k-slices (slice == wave -> W1 index
// stays wave-uniform -> s_load). 4 outer tiles of 128 k; LDS [64][129].
__global__ __launch_bounds__(256) void gemm1(const float* __restrict__ x,
                                             const float* __restrict__ W1,
                                             const float* __restrict__ dinv,
                                             __half2* __restrict__ hs1) {
    __shared__ float xs[64 * 129];   // 33 KB (also reused as reduce buffer)
    int tid = threadIdx.x;
    int r = tid & 63;     // row within block
    int s = tid >> 6;     // k-slice = wave id
    int row0 = blockIdx.x * 64;
    float acc[16];
#pragma unroll
    for (int c = 0; c < 16; c++) acc[c] = 0.f;

    float4 pre[8];
    // prefetch tile k0=0: 64 rows x 128 k = 2048 float4, 8 per thread
#pragma unroll
    for (int l = 0; l < 8; l++) {
        int idx = tid + l * 256;   // 0..2047
        int rr = idx >> 5;         // 0..63
        int f4 = idx & 31;         // 0..31
        int gr = row0 + rr;
        pre[l] = make_float4(0.f, 0.f, 0.f, 0.f);
        if (gr < N_NODES)
            pre[l] = *(const float4*)(x + (size_t)gr * D_IN + f4 * 4);
    }

    for (int k0 = 0; k0 < D_IN; k0 += 128) {
        __syncthreads();
#pragma unroll
        for (int l = 0; l < 8; l++) {
            int idx = tid + l * 256;
            int rr = idx >> 5;
            int f4 = idx & 31;
            int a = rr * 129 + f4 * 4;
            xs[a] = pre[l].x; xs[a + 1] = pre[l].y; xs[a + 2] = pre[l].z; xs[a + 3] = pre[l].w;
        }
        __syncthreads();
        if (k0 + 128 < D_IN) {
#pragma unroll
            for (int l = 0; l < 8; l++) {
                int idx = tid + l * 256;
                int rr = idx >> 5;
                int f4 = idx & 31;
                int gr = row0 + rr;
                pre[l] = make_float4(0.f, 0.f, 0.f, 0.f);
                if (gr < N_NODES)
                    pre[l] = *(const float4*)(x + (size_t)gr * D_IN + (k0 + 128) + f4 * 4);
            }
        }
        const float* wbase = W1 + (k0 + s * 32) * 16;   // wave-uniform
#pragma unroll
        for (int kk = 0; kk < 32; kk++) {
            float xv = xs[r * 129 + s * 32 + kk];
            const float* wr = wbase + kk * 16;
#pragma unroll
            for (int c = 0; c < 16; c++) acc[c] = fmaf(xv, wr[c], acc[c]);
        }
    }
    // cross-slice reduction via LDS (pad 17 -> conflict-free)
    __syncthreads();
#pragma unroll
    for (int c = 0; c < 16; c++) xs[tid * 17 + c] = acc[c];
    __syncthreads();
    if (s == 0) {
        int row = row0 + r;
        if (row < N_NODES) {
            float di = dinv[row];
            __half2 p[8];
#pragma unroll
            for (int i = 0; i < 8; i++) {
                float a0 = xs[r * 17 + 2 * i]       + xs[(r + 64) * 17 + 2 * i]
                         + xs[(r + 128) * 17 + 2 * i] + xs[(r + 192) * 17 + 2 * i];
                float a1 = xs[r * 17 + 2 * i + 1]       + xs[(r + 64) * 17 + 2 * i + 1]
                         + xs[(r + 128) * 17 + 2 * i + 1] + xs[(r + 192) * 17 + 2 * i + 1];
                p[i] = __floats2half2_rn(a0 * di, a1 * di);
            }
            float4* o = (float4*)(hs1 + (size_t)row * 8);
            o[0] = *(float4*)&p[0];
            o[1] = *(float4*)&p[4];
        }
    }
}

// ---------------- Agg layer 1: wave-per-node pull (8 slots x 8 lanes, fp16) --
__global__ __launch_bounds__(256) void agg1(const __half2* __restrict__ hs1,
                                            const float* __restrict__ dinv,
                                            const int* __restrict__ row_start,
                                            const int* __restrict__ deg,
                                            const int* __restrict__ csr,
                                            const float* __restrict__ b1,
                                            const float* __restrict__ W2,
                                            __half2* __restrict__ hs3) {
    int tid = threadIdx.x;
    int node = blockIdx.x * 4 + (tid >> 6);
    if (node >= N_NODES) return;
    int lane = tid & 63;
    int slot = lane >> 3;   // 8 edge slots
    int q = lane & 7;       // half2 index within row (features 2q, 2q+1)
    int start = row_start[node];
    int cnt = deg[node];
    float ax = 0.f, ay = 0.f;
    __half2 v0 = __float2half2_rn(0.f), v1 = __float2half2_rn(0.f);
    int t = slot;
    {
        int sA = (t < cnt) ? csr[start + t] : 0;
        int sB = (t + 8 < cnt) ? csr[start + t + 8] : 0;
        if (t < cnt) v0 = hs1[(size_t)sA * 8 + q];
        if (t + 8 < cnt) v1 = hs1[(size_t)sB * 8 + q];
    }
    for (; t < cnt; t += 8) {
        __half2 vC = v0;
        v0 = v1;
        int tn = t + 16;
        if (tn < cnt) {
            int s = csr[start + tn];
            v1 = hs1[(size_t)s * 8 + q];
        } else {
            v1 = __float2half2_rn(0.f);
        }
        float2 f = __half22float2(vC);
        ax += f.x; ay += f.y;
    }
    ax += __shfl_xor(ax, 8);  ay += __shfl_xor(ay, 8);
    ax += __shfl_xor(ax, 16); ay += __shfl_xor(ay, 16);
    ax += __shfl_xor(ax, 32); ay += __shfl_xor(ay, 32);
    float di = dinv[node];
    float2 self = __half22float2(hs1[(size_t)node * 8 + q]);
    float2 bb = ((const float2*)b1)[q];
    float vx = (ax + self.x) * di + bb.x;
    float vy = (ay + self.y) * di + bb.y;
    vx = vx > 0.f ? vx : 0.f;
    vy = vy > 0.f ? vy : 0.f;
    int c0 = q * 2;
    float o0 = 0.f, o1 = 0.f;
#pragma unroll
    for (int j = 0; j < 8; j++) {
        float ujx = __shfl(vx, j, 8);
        float ujy = __shfl(vy, j, 8);
        const float* w0 = W2 + (2 * j) * 16;
        const float* w1 = W2 + (2 * j + 1) * 16;
        o0 = fmaf(ujx, w0[c0], o0);     o0 = fmaf(ujy, w1[c0], o0);
        o1 = fmaf(ujx, w0[c0 + 1], o1); o1 = fmaf(ujy, w1[c0 + 1], o1);
    }
    if (slot == 0) hs3[(size_t)node * 8 + q] = __floats2half2_rn(o0 * di, o1 * di);
}

// ---------------- Agg layer 2: wave-per-node pull + b2 + log_softmax --------
__global__ __launch_bounds__(256) void agg2(const __half2* __restrict__ hs3,
                                            const float* __restrict__ dinv,
                                            const int* __restrict__ row_start,
                                            const int* __restrict__ deg,
                                            const int* __restrict__ csr,
                                            const float* __restrict__ b2,
                                            float* __restrict__ out) {
    int tid = threadIdx.x;
    int node = blockIdx.x * 4 + (tid >> 6);
    if (node >= N_NODES) return;
    int lane = tid & 63;
    int slot = lane >> 3;
    int q = lane & 7;
    int start = row_start[node];
    int cnt = deg[node];
    float ax = 0.f, ay = 0.f;
    __half2 v0 = __float2half2_rn(0.f), v1 = __float2half2_rn(0.f);
    int t = slot;
    {
        int sA = (t < cnt) ? csr[start + t] : 0;
        int sB = (t + 8 < cnt) ? csr[start + t + 8] : 0;
        if (t < cnt) v0 = hs3[(size_t)sA * 8 + q];
        if (t + 8 < cnt) v1 = hs3[(size_t)sB * 8 + q];
    }
    for (; t < cnt; t += 8) {
        __half2 vC = v0;
        v0 = v1;
        int tn = t + 16;
        if (tn < cnt) {
            int s = csr[start + tn];
            v1 = hs3[(size_t)s * 8 + q];
        } else {
            v1 = __float2half2_rn(0.f);
        }
        float2 f = __half22float2(vC);
        ax += f.x; ay += f.y;
    }
    ax += __shfl_xor(ax, 8);  ay += __shfl_xor(ay, 8);
    ax += __shfl_xor(ax, 16); ay += __shfl_xor(ay, 16);
    ax += __shfl_xor(ax, 32); ay += __shfl_xor(ay, 32);
    float di = dinv[node];
    float2 self = __half22float2(hs3[(size_t)node * 8 + q]);
    float2 bb = ((const float2*)b2)[q];
    float lx = (ax + self.x) * di + bb.x;
    float ly = (ay + self.y) * di + bb.y;
    float m = fmaxf(lx, ly);
#pragma unroll
    for (int mask = 1; mask < 8; mask <<= 1)
        m = fmaxf(m, __shfl_xor(m, mask, 8));
    float ex = expf(lx - m), ey = expf(ly - m);
    float s = ex + ey;
#pragma unroll
    for (int mask = 1; mask < 8; mask <<= 1)
        s += __shfl_xor(s, mask, 8);
    float ls = logf(s);
    if (slot == 0) {
        float2 o = make_float2(lx - m - ls, ly - m - ls);
        ((float2*)out)[(size_t)node * 8 + q] = o;
    }
}

extern "C" void kernel_launch(void* const* d_in, const int* in_sizes, int n_in,
                              void* d_out, int out_size, void* d_ws, size_t ws_size,
                              hipStream_t stream) {
    const float* x  = (const float*)d_in[0];
    const float* W1 = (const float*)d_in[1];
    const float* b1 = (const float*)d_in[2];
    const float* W2 = (const float*)d_in[3];
    const float* b2 = (const float*)d_in[4];
    const int*   ei = (const int*)d_in[5];
    const int* src = ei;
    const int* dst = ei + N_EDGES;
    float* out = (float*)d_out;

    // workspace layout (4B elements):
    int* deg       = (int*)d_ws;                  // 100096
    int* row_start = deg + 100096;                // 100096
    float* dinv    = (float*)(row_start + 100096);// 100096
    int* bcnt      = (int*)(dinv + 100096);       // 1024
    int* bstart    = bcnt + 1024;                 // 1024
    int* bcur      = bstart + 1024;               // 1024
    int* bhist     = bcur + 1024;                 // 250*800 = 200000
    unsigned int* ebuf = (unsigned int*)(bhist + 200000); // 6400000
    __half2* hs1   = (__half2*)(ebuf + N_EDGES);  // 800000 x 4B
    __half2* hs3   = hs1 + 800000;                // 800000 x 4B

    hipMemsetAsync(bcnt, 0, NB * sizeof(int), stream);
    p1_hist<<<NT2, 1024, 0, stream>>>(dst, bhist, bcnt);
    p2_scan<<<1, 1024, 0, stream>>>(bcnt, bstart, bcur);
    p2_scatter<<<NT2, 1024, 0, stream>>>(src, dst, bhist, bcur, ebuf);
    p3_build<<<NB, 512, 0, stream>>>(ebuf, bstart, bcnt, row_start, deg, dinv);
    gemm1<<<(N_NODES + 63) / 64, 256, 0, stream>>>(x, W1, dinv, hs1);
    agg1<<<(N_NODES + 3) / 4, 256, 0, stream>>>(hs1, dinv, row_start, deg, (const int*)ebuf, b1, W2, hs3);
    agg2<<<(N_NODES + 3) / 4, 256, 0, stream>>>(hs3, dinv, row_start, deg, (const int*)ebuf, b2, out);
}

// Round 7
// 584.926 us; speedup vs baseline: 1.1221x; 1.1221x over previous
//
#include <hip/hip_runtime.h>
#include <hip/hip_fp16.h>
#include <math.h>

#define N_NODES 100000
#define N_EDGES 6400000
#define D_IN 512
#define D_HID 16

// ---- bucketed counting-sort parameters ----
#define BSHIFT 7
#define BNODES 128                                   // nodes per bucket
#define NB ((N_NODES + BNODES - 1) / BNODES)         // 782 buckets
#define NBP 800                                      // bhist row pitch
#define P2T 25600                                    // edges per tile (p1/p2)
#define NT2 (N_EDGES / P2T)                          // 250 (exact)
#define CAP 9728                                     // max edges/bucket (mean 8184 + ~17 sigma)

typedef _Float16 f16x8 __attribute__((ext_vector_type(8)));
typedef float f32x4 __attribute__((ext_vector_type(4)));

// ---------------- pass 1: per-tile bucket histogram (saved) ----------------
__global__ __launch_bounds__(1024) void p1_hist(const int* __restrict__ dst,
                                                int* __restrict__ bhist,
                                                int* __restrict__ bcnt) {
    __shared__ int h[NB];
    int tid = threadIdx.x;
    if (tid < NB) h[tid] = 0;
    __syncthreads();
    int base = blockIdx.x * P2T;
#pragma unroll
    for (int k = 0; k < P2T / 1024; k++) {
        int e = base + k * 1024 + tid;
        atomicAdd(&h[dst[e] >> BSHIFT], 1);
    }
    __syncthreads();
    if (tid < NB) {
        int c = h[tid];
        bhist[blockIdx.x * NBP + tid] = c;
        if (c) atomicAdd(&bcnt[tid], c);
    }
}

// ---------------- pass 2a: scan bucket counts (1 block) ----------------
__global__ void p2_scan(const int* __restrict__ bcnt, int* __restrict__ bstart,
                        int* __restrict__ bcur) {
    __shared__ int sd[1024];
    int tid = threadIdx.x;  // 1024 threads
    int v = (tid < NB) ? bcnt[tid] : 0;
    sd[tid] = v;
    __syncthreads();
    for (int off = 1; off < 1024; off <<= 1) {
        int u = (tid >= off) ? sd[tid - off] : 0;
        __syncthreads();
        sd[tid] += u;
        __syncthreads();
    }
    if (tid < NB) {
        int ex = sd[tid] - v;
        bstart[tid] = ex;
        bcur[tid] = ex;
    }
}

// ---------------- pass 2b: LDS-sorted multisplit scatter ----------------
__global__ __launch_bounds__(1024) void p2_scatter(const int* __restrict__ src,
                                                   const int* __restrict__ dst,
                                                   const int* __restrict__ bhist,
                                                   int* __restrict__ bcur,
                                                   unsigned int* __restrict__ staged) {
    __shared__ unsigned int sbuf[P2T];   // 100 KB
    __shared__ int loc[NB + 1];
    __shared__ int lcur[NB];
    __shared__ int gbase[NB];
    __shared__ int sd[1024];
    int tid = threadIdx.x;
    int blk = blockIdx.x;
    int c = 0;
    if (tid < NB) {
        c = bhist[blk * NBP + tid];
        gbase[tid] = c ? atomicAdd(&bcur[tid], c) : 0;
    }
    sd[tid] = (tid < NB) ? c : 0;
    __syncthreads();
    for (int off = 1; off < 1024; off <<= 1) {
        int u = (tid >= off) ? sd[tid - off] : 0;
        __syncthreads();
        sd[tid] += u;
        __syncthreads();
    }
    if (tid < NB) {
        int ex = sd[tid] - c;
        loc[tid] = ex;
        lcur[tid] = ex;
    }
    if (tid == 0) loc[NB] = P2T;  // sentinel (tile hist sums to P2T exactly)
    __syncthreads();
    int base = blk * P2T;
#pragma unroll
    for (int k = 0; k < P2T / 1024; k++) {
        int e = base + k * 1024 + tid;
        int d = dst[e];
        int b = d >> BSHIFT;
        int pos = atomicAdd(&lcur[b], 1);
        sbuf[pos] = ((unsigned int)src[e] << BSHIFT) | (unsigned int)(d & (BNODES - 1));
    }
    __syncthreads();
#pragma unroll
    for (int k = 0; k < P2T / 1024; k++) {
        int j = k * 1024 + tid;
        int lo = 0, hi = NB;
        while (hi - lo > 1) {
            int mid = (lo + hi) >> 1;
            if (loc[mid] <= j) lo = mid; else hi = mid;
        }
        staged[gbase[lo] + (j - loc[lo])] = sbuf[j];
    }
}

// ---------------- pass 3: per-bucket CSR build (+deg, row_start, dinv) ------
__global__ __launch_bounds__(512) void p3_build(unsigned int* __restrict__ ebuf,
                                                const int* __restrict__ bstart,
                                                const int* __restrict__ bcnt,
                                                int* __restrict__ row_start,
                                                int* __restrict__ deg,
                                                float* __restrict__ dinv) {
    __shared__ unsigned int buf[CAP];
    __shared__ int cnt[BNODES];
    __shared__ int cur[BNODES];
    int b = blockIdx.x;
    int tid = threadIdx.x;
    int ebase = bstart[b];
    int ecnt = bcnt[b];
    if (ecnt > CAP) ecnt = CAP;  // statistically impossible; guards LDS
    if (tid < BNODES) cnt[tid] = 0;
    __syncthreads();
    for (int i = tid; i < ecnt; i += 512) {
        unsigned int v = ebuf[ebase + i];
        buf[i] = v;
        atomicAdd(&cnt[v & (BNODES - 1)], 1);
    }
    __syncthreads();
    int c = 0;
    if (tid < BNODES) {
        c = cnt[tid];
        cur[tid] = c;
    }
    __syncthreads();
    for (int off = 1; off < BNODES; off <<= 1) {
        int u = 0;
        if (tid < BNODES && tid >= off) u = cur[tid - off];
        __syncthreads();
        if (tid < BNODES) cur[tid] += u;
        __syncthreads();
    }
    int excl = 0;
    if (tid < BNODES) excl = cur[tid] - c;
    int node = b * BNODES + tid;
    if (tid < BNODES && node < N_NODES) {
        row_start[node] = ebase + excl;
        deg[node] = c;
        dinv[node] = rsqrtf((float)c + 1.0f);  // +1 self-loop
    }
    __syncthreads();
    if (tid < BNODES) cur[tid] = excl;  // local cursor
    __syncthreads();
    for (int i = tid; i < ecnt; i += 512) {
        unsigned int v = buf[i];
        int pos = atomicAdd(&cur[v & (BNODES - 1)], 1);
        ebuf[ebase + pos] = v >> BSHIFT;  // final CSR: src id
    }
}

// ---------------- GEMM1 (MFMA): hs1 = fp16((x @ W1) * dinv[row]) ----------
// One wave per 16 rows; W1 held as 16 B-fragments in registers; K-loop is
// 16 x {2 coalesced float4 loads -> cvt fp16 -> mfma_f32_16x16x32_f16}.
// A/B use the same (group,elem)->k mapping (contiguous 8), which is correct
// for symmetric 16x16 fragment layouts regardless of HW-internal k order.
// C/D layout (HW-verified): col = lane&15, row = (lane>>4)*4 + reg.
__global__ __launch_bounds__(256) void gemm1(const float* __restrict__ x,
                                             const float* __restrict__ W1,
                                             const float* __restrict__ dinv,
                                             __half* __restrict__ hs1) {
    int tid = threadIdx.x;
    int lane = tid & 63;
    int wave = tid >> 6;
    int m = lane & 15;      // A row within tile / B col / C col
    int kg = lane >> 4;     // k-group 0..3
    int row0 = (blockIdx.x * 4 + wave) * 16;
    int rowA = row0 + m;
    int rowSafe = rowA < N_NODES ? rowA : N_NODES - 1;

    // B fragments: bf[t][j] = W1[t*32 + kg*8 + j][m]
    f16x8 bf[16];
#pragma unroll
    for (int t = 0; t < 16; t++) {
        const float* wp = W1 + (size_t)(t * 32 + kg * 8) * 16 + m;
#pragma unroll
        for (int j = 0; j < 8; j++)
            bf[t][j] = (_Float16)wp[j * 16];
    }

    f32x4 acc = {0.f, 0.f, 0.f, 0.f};
    const float* xp = x + (size_t)rowSafe * D_IN + kg * 8;
#pragma unroll
    for (int t = 0; t < 16; t++) {
        float4 a0 = *(const float4*)(xp + t * 32);
        float4 a1 = *(const float4*)(xp + t * 32 + 4);
        f16x8 af;
        af[0] = (_Float16)a0.x; af[1] = (_Float16)a0.y;
        af[2] = (_Float16)a0.z; af[3] = (_Float16)a0.w;
        af[4] = (_Float16)a1.x; af[5] = (_Float16)a1.y;
        af[6] = (_Float16)a1.z; af[7] = (_Float16)a1.w;
        acc = __builtin_amdgcn_mfma_f32_16x16x32_f16(af, bf[t], acc, 0, 0, 0);
    }
    // epilogue: lane holds D[kg*4+i][m]
#pragma unroll
    for (int i = 0; i < 4; i++) {
        int rr = row0 + kg * 4 + i;
        if (rr < N_NODES) {
            float di = dinv[rr];
            hs1[(size_t)rr * 16 + m] = (__half)(acc[i] * di);
        }
    }
}

// ---------------- Agg layer 1: wave-per-node pull (8 slots x 8 lanes, fp16) --
__global__ __launch_bounds__(256) void agg1(const __half2* __restrict__ hs1,
                                            const float* __restrict__ dinv,
                                            const int* __restrict__ row_start,
                                            const int* __restrict__ deg,
                                            const int* __restrict__ csr,
                                            const float* __restrict__ b1,
                                            const float* __restrict__ W2,
                                            __half2* __restrict__ hs3) {
    int tid = threadIdx.x;
    int node = blockIdx.x * 4 + (tid >> 6);
    if (node >= N_NODES) return;
    int lane = tid & 63;
    int slot = lane >> 3;   // 8 edge slots
    int q = lane & 7;       // half2 index within row (features 2q, 2q+1)
    int start = row_start[node];
    int cnt = deg[node];
    float ax = 0.f, ay = 0.f;
    __half2 v0 = __float2half2_rn(0.f), v1 = __float2half2_rn(0.f);
    int t = slot;
    {
        int sA = (t < cnt) ? csr[start + t] : 0;
        int sB = (t + 8 < cnt) ? csr[start + t + 8] : 0;
        if (t < cnt) v0 = hs1[(size_t)sA * 8 + q];
        if (t + 8 < cnt) v1 = hs1[(size_t)sB * 8 + q];
    }
    for (; t < cnt; t += 8) {
        __half2 vC = v0;
        v0 = v1;
        int tn = t + 16;
        if (tn < cnt) {
            int s = csr[start + tn];
            v1 = hs1[(size_t)s * 8 + q];
        } else {
            v1 = __float2half2_rn(0.f);
        }
        float2 f = __half22float2(vC);
        ax += f.x; ay += f.y;
    }
    ax += __shfl_xor(ax, 8);  ay += __shfl_xor(ay, 8);
    ax += __shfl_xor(ax, 16); ay += __shfl_xor(ay, 16);
    ax += __shfl_xor(ax, 32); ay += __shfl_xor(ay, 32);
    float di = dinv[node];
    float2 self = __half22float2(hs1[(size_t)node * 8 + q]);
    float2 bb = ((const float2*)b1)[q];
    float vx = (ax + self.x) * di + bb.x;
    float vy = (ay + self.y) * di + bb.y;
    vx = vx > 0.f ? vx : 0.f;
    vy = vy > 0.f ? vy : 0.f;
    int c0 = q * 2;
    float o0 = 0.f, o1 = 0.f;
#pragma unroll
    for (int j = 0; j < 8; j++) {
        float ujx = __shfl(vx, j, 8);
        float ujy = __shfl(vy, j, 8);
        const float* w0 = W2 + (2 * j) * 16;
        const float* w1 = W2 + (2 * j + 1) * 16;
        o0 = fmaf(ujx, w0[c0], o0);     o0 = fmaf(ujy, w1[c0], o0);
        o1 = fmaf(ujx, w0[c0 + 1], o1); o1 = fmaf(ujy, w1[c0 + 1], o1);
    }
    if (slot == 0) hs3[(size_t)node * 8 + q] = __floats2half2_rn(o0 * di, o1 * di);
}

// ---------------- Agg layer 2: wave-per-node pull + b2 + log_softmax --------
__global__ __launch_bounds__(256) void agg2(const __half2* __restrict__ hs3,
                                            const float* __restrict__ dinv,
                                            const int* __restrict__ row_start,
                                            const int* __restrict__ deg,
                                            const int* __restrict__ csr,
                                            const float* __restrict__ b2,
                                            float* __restrict__ out) {
    int tid = threadIdx.x;
    int node = blockIdx.x * 4 + (tid >> 6);
    if (node >= N_NODES) return;
    int lane = tid & 63;
    int slot = lane >> 3;
    int q = lane & 7;
    int start = row_start[node];
    int cnt = deg[node];
    float ax = 0.f, ay = 0.f;
    __half2 v0 = __float2half2_rn(0.f), v1 = __float2half2_rn(0.f);
    int t = slot;
    {
        int sA = (t < cnt) ? csr[start + t] : 0;
        int sB = (t + 8 < cnt) ? csr[start + t + 8] : 0;
        if (t < cnt) v0 = hs3[(size_t)sA * 8 + q];
        if (t + 8 < cnt) v1 = hs3[(size_t)sB * 8 + q];
    }
    for (; t < cnt; t += 8) {
        __half2 vC = v0;
        v0 = v1;
        int tn = t + 16;
        if (tn < cnt) {
            int s = csr[start + tn];
            v1 = hs3[(size_t)s * 8 + q];
        } else {
            v1 = __float2half2_rn(0.f);
        }
        float2 f = __half22float2(vC);
        ax += f.x; ay += f.y;
    }
    ax += __shfl_xor(ax, 8);  ay += __shfl_xor(ay, 8);
    ax += __shfl_xor(ax, 16); ay += __shfl_xor(ay, 16);
    ax += __shfl_xor(ax, 32); ay += __shfl_xor(ay, 32);
    float di = dinv[node];
    float2 self = __half22float2(hs3[(size_t)node * 8 + q]);
    float2 bb = ((const float2*)b2)[q];
    float lx = (ax + self.x) * di + bb.x;
    float ly = (ay + self.y) * di + bb.y;
    float m = fmaxf(lx, ly);
#pragma unroll
    for (int mask = 1; mask < 8; mask <<= 1)
        m = fmaxf(m, __shfl_xor(m, mask, 8));
    float ex = expf(lx - m), ey = expf(ly - m);
    float s = ex + ey;
#pragma unroll
    for (int mask = 1; mask < 8; mask <<= 1)
        s += __shfl_xor(s, mask, 8);
    float ls = logf(s);
    if (slot == 0) {
        float2 o = make_float2(lx - m - ls, ly - m - ls);
        ((float2*)out)[(size_t)node * 8 + q] = o;
    }
}

extern "C" void kernel_launch(void* const* d_in, const int* in_sizes, int n_in,
                              void* d_out, int out_size, void* d_ws, size_t ws_size,
                              hipStream_t stream) {
    const float* x  = (const float*)d_in[0];
    const float* W1 = (const float*)d_in[1];
    const float* b1 = (const float*)d_in[2];
    const float* W2 = (const float*)d_in[3];
    const float* b2 = (const float*)d_in[4];
    const int*   ei = (const int*)d_in[5];
    const int* src = ei;
    const int* dst = ei + N_EDGES;
    float* out = (float*)d_out;

    // workspace layout (4B elements):
    int* deg       = (int*)d_ws;                  // 100096
    int* row_start = deg + 100096;                // 100096
    float* dinv    = (float*)(row_start + 100096);// 100096
    int* bcnt      = (int*)(dinv + 100096);       // 1024
    int* bstart    = bcnt + 1024;                 // 1024
    int* bcur      = bstart + 1024;               // 1024
    int* bhist     = bcur + 1024;                 // 250*800 = 200000
    unsigned int* ebuf = (unsigned int*)(bhist + 200000); // 6400000
    __half2* hs1   = (__half2*)(ebuf + N_EDGES);  // 800000 x 4B
    __half2* hs3   = hs1 + 800000;                // 800000 x 4B

    hipMemsetAsync(bcnt, 0, NB * sizeof(int), stream);
    p1_hist<<<NT2, 1024, 0, stream>>>(dst, bhist, bcnt);
    p2_scan<<<1, 1024, 0, stream>>>(bcnt, bstart, bcur);
    p2_scatter<<<NT2, 1024, 0, stream>>>(src, dst, bhist, bcur, ebuf);
    p3_build<<<NB, 512, 0, stream>>>(ebuf, bstart, bcnt, row_start, deg, dinv);
    gemm1<<<(N_NODES + 63) / 64, 256, 0, stream>>>(x, W1, dinv, (__half*)hs1);
    agg1<<<(N_NODES + 3) / 4, 256, 0, stream>>>(hs1, dinv, row_start, deg, (const int*)ebuf, b1, W2, hs3);
    agg2<<<(N_NODES + 3) / 4, 256, 0, stream>>>(hs3, dinv, row_start, deg, (const int*)ebuf, b2, out);
}